// Round 12
// baseline (80.175 us; speedup 1.0000x reference)
//
#include <hip/hip_runtime.h>

#define NB 16
#define HH 1024
#define WW 1024
#define SH 16          // strip height (output rows per block)
#define D  6           // prefetch depth: raw rows in flight per thread

#define EPS1 2e-4f     // edge-threshold confidence margin (f32 err bound ~4e-6)
#define EPS2 1e-4f     // final-threshold confidence margin (f32 err bound ~4e-6)

typedef float f32x4 __attribute__((ext_vector_type(4)));
typedef float f32x2 __attribute__((ext_vector_type(2)));

// Cold exact-path: recompute one pixel in f64 straight from global memory
// (identical to R9's fallback, which scored absmax 0.0 vs the np reference).
__device__ __noinline__ float aes_exact_g(const float* __restrict__ m,
                                          int gy, int gx,
                                          float bsf, float esf, float fthr)
{
    const double bfd   = (double)bsf / 3.0;
    const double ethrd = 0.5 * (double)esf;
    const double fthrd = (double)fthr;
    const double w25d  = (double)(1.0f / 25.0f);

    double s25 = 0.0, s9 = 0.0;
    for (int dy = -2; dy <= 2; ++dy)
        for (int dx = -2; dx <= 2; ++dx) {
            int yy = gy + dy, xx = gx + dx;
            double v = 0.0;
            if ((unsigned)yy < (unsigned)HH && (unsigned)xx < (unsigned)WW)
                v = (double)m[(size_t)yy * WW + xx];
            s25 += v;
            if (dy >= -1 && dy <= 1 && dx >= -1 && dx <= 1) s9 += v;
        }
    double c      = (double)m[(size_t)gy * WW + gx];
    double edges  = fabs(9.0 * c - s9);
    double sbase  = s25 * w25d;
    double smooth = c * (1.0 - bfd) + sbase * bfd;
    double result = (edges > ethrd) ? smooth : c;
    return (result > fthrd) ? 1.0f : 0.0f;
}

__global__ __launch_bounds__(256)
void aes_kernel(const float* __restrict__ mask,
                const float* __restrict__ blur_strength,
                const float* __restrict__ edge_sensitivity,
                const float* __restrict__ final_threshold,
                float* __restrict__ out)
{
    const int b  = blockIdx.z;
    const int y0 = blockIdx.y * SH;
    const float* m = mask + (size_t)b * (HH * WW);

    const float bsf    = blur_strength[b];
    const float esf    = edge_sensitivity[b];
    const float fthr   = final_threshold[b];
    const float ethr   = 0.5f * esf;          // exact in f32
    const float bff    = bsf / 3.0f;
    const float onembf = 1.0f - bff;
    const float w25f   = 1.0f / 25.0f;

    // 4 waves x 64 lanes x 4 cols = full 1024-wide row; no LDS, no barriers
    const int lane = threadIdx.x & 63;
    const int wv   = threadIdx.x >> 6;
    const int x0   = wv * 256 + lane * 4;     // first owned col (16B aligned)
    const bool isL = (lane == 0);
    const bool isR = (lane == 63);
    const bool lok = (x0 > 0);
    const bool rok = (x0 + 4 < WW);

    f32x4 ring[D];     // raw rows in flight (prefetch ring)
    f32x2 ering[D];    // wave-seam halo: lane0 holds left 2 cols, lane63 right 2

    // load raw row (y0+RELROW) into ring slot SLOT; zeros for OOB rows
#define LOADRAW(SLOT, RELROW)                                               \
    {                                                                       \
        const int gy = y0 + (RELROW);                                       \
        const bool rv = (unsigned)gy < (unsigned)HH;                        \
        f32x4 q = {0.f, 0.f, 0.f, 0.f};                                     \
        f32x2 e = {0.f, 0.f};                                               \
        if (rv) {                                                           \
            const float* rp = m + (size_t)gy * WW + x0;                     \
            q = *(const f32x4*)rp;              /* coalesced 1KB/wave */    \
            if (isL && lok) e = *(const f32x2*)(rp - 2);  /* 1 lane */      \
            if (isR && rok) e = *(const f32x2*)(rp + 4);  /* 1 lane */      \
        }                                                                   \
        ring[(SLOT)] = q;                                                   \
        ering[(SLOT)] = e;                                                  \
    }

    // rolling h-sum rings over 5 rows (proven math from R2..R11)
    float h5[5][4], h3[5][4], cc[5][4];

    // turn ring slot SLOT into h5/h3/cc ring entry K (halo via shuffles)
#define CONVERT(SLOT, K)                                                    \
    {                                                                       \
        f32x4 q = ring[(SLOT)];                                             \
        f32x2 e = ering[(SLOT)];                                            \
        float a2 = q.x, a3 = q.y, a4 = q.z, a5 = q.w;                       \
        float a0 = __shfl_up(a4, 1);    /* lane-1's col x0-2 */             \
        float a1 = __shfl_up(a5, 1);    /* lane-1's col x0-1 */             \
        float a6 = __shfl_down(a2, 1);  /* lane+1's col x0+4 */             \
        float a7 = __shfl_down(a3, 1);  /* lane+1's col x0+5 */             \
        if (isL) { a0 = e.x; a1 = e.y; }   /* seam / image edge (zeros) */  \
        if (isR) { a6 = e.x; a7 = e.y; }                                    \
        float s5 = ((a0 + a1) + (a2 + a3)) + a4;                            \
        h5[(K)][0] = s5; s5 = s5 - a0 + a5;                                 \
        h5[(K)][1] = s5; s5 = s5 - a1 + a6;                                 \
        h5[(K)][2] = s5; s5 = s5 - a2 + a7;                                 \
        h5[(K)][3] = s5;                                                    \
        float s3 = (a1 + a2) + a3;                                          \
        h3[(K)][0] = s3; s3 = s3 - a1 + a4;                                 \
        h3[(K)][1] = s3; s3 = s3 - a2 + a5;                                 \
        h3[(K)][2] = s3; s3 = s3 - a3 + a6;                                 \
        h3[(K)][3] = s3;                                                    \
        cc[(K)][0] = a2; cc[(K)][1] = a3; cc[(K)][2] = a4; cc[(K)][3] = a5; \
    }

    // ---- prologue: fill prefetch ring with rows -2 .. D-3 ----
    #pragma unroll
    for (int s = 0; s < D; ++s)
        LOADRAW(s, -2 + s)

    // convert rows -2..1 (slots 0..3) and refill those slots with rows 4..7
    #pragma unroll
    for (int t = 0; t < 4; ++t) {
        CONVERT(t, t)
        LOADRAW(t, -2 + D + t)
    }

    float* op0 = out + (size_t)b * (HH * WW) + (size_t)y0 * WW + x0;

    // ---- main loop: row r consumes raw row r+2 (slot (r+4)%D) ----
    #pragma unroll
    for (int r = 0; r < SH; ++r) {
        CONVERT((r + 4) % D, (r + 4) % 5)
        if (r + 2 + D <= SH + 1)              // prefetch row r+2+D if needed
            LOADRAW((r + 4) % D, r + 2 + D)

        const int i0 = r % 5, i1 = (r + 1) % 5, i2 = (r + 2) % 5;
        const int i3 = (r + 3) % 5, i4 = (r + 4) % 5;

        f32x4 ov;
        #pragma unroll
        for (int c = 0; c < 4; ++c) {
            float sum25  = ((h5[i0][c] + h5[i1][c]) + (h5[i2][c] + h5[i3][c]))
                         + h5[i4][c];
            float s9     = h3[i1][c] + h3[i2][c] + h3[i3][c];
            float center = cc[i2][c];

            float edges  = fabsf(9.0f * center - s9);
            float sbase  = sum25 * w25f;
            float smooth = center * onembf + sbase * bff;

            bool isedge = edges > ethr;
            // no-edge branch compares EXACT center vs EXACT fthr -> always safe
            bool conf = (fabsf(edges - ethr) > EPS1) &&
                        (!isedge || (fabsf(smooth - fthr) > EPS2));
            float res = isedge ? smooth : center;
            float o   = (res > fthr) ? 1.0f : 0.0f;

            if (!conf)
                o = aes_exact_g(m, y0 + r, x0 + c, bsf, esf, fthr);

            ov[c] = o;          // c is compile-time after unroll
        }
        *(f32x4*)(op0 + (size_t)r * WW) = ov;
    }
#undef LOADRAW
#undef CONVERT
}

extern "C" void kernel_launch(void* const* d_in, const int* in_sizes, int n_in,
                              void* d_out, int out_size, void* d_ws, size_t ws_size,
                              hipStream_t stream) {
    const float* mask = (const float*)d_in[0];
    const float* bs   = (const float*)d_in[1];
    const float* es   = (const float*)d_in[2];
    const float* ft   = (const float*)d_in[3];
    float* out = (float*)d_out;

    dim3 grid(1, HH / SH, NB);   // 1 x 64 x 16 = 1024 blocks (full-width strips)
    aes_kernel<<<grid, 256, 0, stream>>>(mask, bs, es, ft, out);
}

// Round 13
// 45.289 us; speedup vs baseline: 1.7703x; 1.7703x over previous
//
#include <hip/hip_runtime.h>

#define NB 16
#define HH 1024
#define WW 1024
#define TW 128         // tile width  (output)
#define TH 32          // tile height (output)
#define NT 8           // tiles per vertical strip (256 rows)
#define LC 136         // staged cols: global x in [tile_x-4, tile_x+132)
#define LR 36          // staged rows: global y in [tile_y-2, tile_y+34)
#define C4 (LC / 4)    // 34 float4 groups per row
#define N4 (LR * C4)   // 1224 float4 groups per tile
#define GX (WW / TW)        // 8
#define GY (HH / (NT * TH)) // 4

#define EPS1 2e-4f     // edge-threshold confidence margin (f32 err bound ~4e-6)
#define EPS2 1e-4f     // final-threshold confidence margin (f32 err bound ~4e-6)

typedef float f32x4 __attribute__((ext_vector_type(4)));

__device__ __forceinline__ void gload_lds16(const float* g, float* l) {
    __builtin_amdgcn_global_load_lds(
        (const __attribute__((address_space(1))) void*)g,
        (__attribute__((address_space(3))) void*)l, 16, 0, 0);
}

// Cold exact-path: recompute one pixel in f64 from LDS (identical math to the
// R1 kernel that scored absmax 0.0 against the np/f64 reference).
__device__ __noinline__ float aes_exact(const float (*raw)[LC], int lr, int lc,
                                        float bsf, float esf, float fthr)
{
    const double bfd   = (double)bsf / 3.0;
    const double ethrd = 0.5 * (double)esf;
    const double fthrd = (double)fthr;
    const double w25d  = (double)(1.0f / 25.0f);

    double s25 = 0.0, s9 = 0.0;
    for (int dy = 0; dy < 5; ++dy)
        for (int dx = 0; dx < 5; ++dx) {
            double v = (double)raw[lr + dy][lc + dx];
            s25 += v;
            if (dy >= 1 && dy <= 3 && dx >= 1 && dx <= 3) s9 += v;
        }
    double c      = (double)raw[lr + 2][lc + 2];
    double edges  = fabs(9.0 * c - s9);
    double sbase  = s25 * w25d;
    double smooth = c * (1.0 - bfd) + sbase * bfd;
    double result = (edges > ethrd) ? smooth : c;
    return (result > fthrd) ? 1.0f : 0.0f;
}

__global__ __launch_bounds__(256)
void aes_kernel(const float* __restrict__ mask,
                const float* __restrict__ blur_strength,
                const float* __restrict__ edge_sensitivity,
                const float* __restrict__ final_threshold,
                float* __restrict__ out)
{
    __shared__ float raw[2][LR][LC];   // 39,168 B -> 4 blocks/CU

    const int b       = blockIdx.z;
    const int tile_x  = blockIdx.x * TW;
    const int strip_y = blockIdx.y * (NT * TH);
    const float* m = mask + (size_t)b * (HH * WW);

    const float bsf    = blur_strength[b];
    const float esf    = edge_sensitivity[b];
    const float fthr   = final_threshold[b];
    const float ethr   = 0.5f * esf;          // exact in f32
    const float bff    = bsf / 3.0f;
    const float onembf = 1.0f - bff;
    const float w25f   = 1.0f / 25.0f;

    // thread -> 4 cols x 4 rows micro-tile (R7's proven layout)
    const int tx  = threadIdx.x & 31;
    const int ty  = threadIdx.x >> 5;
    const int lr0 = ty * 4;
    const int lc0 = 4 * tx + 2;

    const bool zl = (blockIdx.x == 0);        // left-halo cols OOB
    const bool zr = (blockIdx.x == GX - 1);   // right-halo cols OOB

    // ---- DMA-stage tile T into LDS buffer BUF (clamped addrs, fixed later)
#define STAGE_DMA(T, BUF)                                                   \
    {                                                                       \
        const int ty0 = strip_y + (T) * TH;                                 \
        _Pragma("unroll")                                                   \
        for (int k = 0; k < 5; ++k) {                                       \
            int i = (int)threadIdx.x + k * 256;                             \
            if (i < N4) {                                                   \
                int row = i / C4, c4 = i - row * C4;                        \
                int gy = ty0 - 2 + row;                                     \
                gy = gy < 0 ? 0 : (gy > HH - 1 ? HH - 1 : gy);              \
                int gx = tile_x - 4 + 4 * c4;                               \
                gx = gx < 0 ? 0 : (gx > WW - 4 ? WW - 4 : gx);              \
                gload_lds16(m + (size_t)gy * WW + gx,                       \
                            &raw[(BUF)][0][0] + (size_t)i * 4);             \
            }                                                               \
        }                                                                   \
        __builtin_amdgcn_sched_barrier(0);  /* pin DMA issue order */       \
    }

    // ---- zero the halo cells whose clamped DMA loads carried garbage ----
#define FIXUP(T, BUF)                                                       \
    {                                                                       \
        const bool ztop = (blockIdx.y == 0)      && ((T) == 0);             \
        const bool zbot = (blockIdx.y == GY - 1) && ((T) == NT - 1);        \
        if (zl | zr | ztop | zbot) {                                        \
            const f32x4 z4 = {0.f, 0.f, 0.f, 0.f};                         \
            const int tid = (int)threadIdx.x;                               \
            if (zl && tid < LR) *(f32x4*)&raw[(BUF)][tid][0] = z4;          \
            if (zr && tid < LR) *(f32x4*)&raw[(BUF)][tid][LC - 4] = z4;     \
            if (ztop && tid < 2 * C4) {                                     \
                int rr = tid / C4, cc4 = tid - rr * C4;                     \
                *(f32x4*)&raw[(BUF)][rr][4 * cc4] = z4;                     \
            }                                                               \
            if (zbot && tid < 2 * C4) {                                     \
                int rr = 34 + tid / C4, cc4 = tid - (tid / C4) * C4;        \
                *(f32x4*)&raw[(BUF)][rr][4 * cc4] = z4;                     \
            }                                                               \
            asm volatile("s_waitcnt lgkmcnt(0)" ::: "memory");              \
            __builtin_amdgcn_s_barrier();                                   \
        }                                                                   \
    }

#define LOADROW(RB, ROWIDX, K)                                              \
    {                                                                       \
        const float* rp = &RB[(ROWIDX)][0];                                 \
        float2 u0 = *(const float2*)(rp + lc0);        /* 8B aligned  */    \
        float4 u1 = *(const float4*)(rp + lc0 + 2);    /* 16B aligned */    \
        float2 u2 = *(const float2*)(rp + lc0 + 6);    /* 8B aligned  */    \
        float a0 = u0.x, a1 = u0.y, a2 = u1.x, a3 = u1.y;                   \
        float a4 = u1.z, a5 = u1.w, a6 = u2.x, a7 = u2.y;                   \
        float s5 = ((a0 + a1) + (a2 + a3)) + a4;                            \
        h5[(K)][0] = s5; s5 = s5 - a0 + a5;                                 \
        h5[(K)][1] = s5; s5 = s5 - a1 + a6;                                 \
        h5[(K)][2] = s5; s5 = s5 - a2 + a7;                                 \
        h5[(K)][3] = s5;                                                    \
        float s3 = (a1 + a2) + a3;                                          \
        h3[(K)][0] = s3; s3 = s3 - a1 + a4;                                 \
        h3[(K)][1] = s3; s3 = s3 - a2 + a5;                                 \
        h3[(K)][2] = s3; s3 = s3 - a3 + a6;                                 \
        h3[(K)][3] = s3;                                                    \
        cc[(K)][0] = a2; cc[(K)][1] = a3; cc[(K)][2] = a4; cc[(K)][3] = a5; \
    }

    // ---- compute tile T from LDS buffer BUF, store results (R7's body) ----
#define COMPUTE(BUF, T)                                                     \
    {                                                                       \
        const int tile_y = strip_y + (T) * TH;                              \
        const float (*rb)[LC] = raw[(BUF)];                                 \
        float h5[5][4], h3[5][4], cc[5][4];                                 \
        _Pragma("unroll")                                                   \
        for (int k = 0; k < 4; ++k)                                         \
            LOADROW(rb, lr0 + k, k)                                         \
        float* op = out + (size_t)b * (HH * WW)                             \
                        + (size_t)(tile_y + ty * 4) * WW + tile_x + 4 * tx; \
        _Pragma("unroll")                                                   \
        for (int r = 0; r < 4; ++r) {                                       \
            LOADROW(rb, lr0 + r + 4, (r + 4) % 5)                           \
            const int i0 = r % 5, i1 = (r + 1) % 5, i2 = (r + 2) % 5;       \
            const int i3 = (r + 3) % 5, i4 = (r + 4) % 5;                   \
            f32x4 ov;                                                       \
            _Pragma("unroll")                                               \
            for (int c = 0; c < 4; ++c) {                                   \
                float sum25  = ((h5[i0][c] + h5[i1][c])                     \
                              + (h5[i2][c] + h5[i3][c])) + h5[i4][c];       \
                float s9     = h3[i1][c] + h3[i2][c] + h3[i3][c];           \
                float center = cc[i2][c];                                   \
                float edges  = fabsf(9.0f * center - s9);                   \
                float sbase  = sum25 * w25f;                                \
                float smooth = center * onembf + sbase * bff;               \
                bool isedge = edges > ethr;                                 \
                bool conf = (fabsf(edges - ethr) > EPS1) &&                 \
                            (!isedge || (fabsf(smooth - fthr) > EPS2));     \
                float res = isedge ? smooth : center;                       \
                float o   = (res > fthr) ? 1.0f : 0.0f;                     \
                if (!conf)                                                  \
                    o = aes_exact(rb, lr0 + r, lc0 + c, bsf, esf, fthr);    \
                ov[c] = o;                                                  \
            }                                                               \
            *(f32x4*)(op + (size_t)r * WW) = ov;                            \
        }                                                                   \
    }

    // ------- counted-vmcnt pipeline: loads stay in flight across barriers --
    STAGE_DMA(0, 0)

    #pragma unroll
    for (int t = 0; t < NT; ++t) {
        // queue at this point (oldest first): D(t)=5, S(t-1)<=4.
        // t==0: only D(0)=5 outstanding -> drain it fully.
        if (t == 0) { asm volatile("s_waitcnt vmcnt(0)" ::: "memory"); }
        else        { asm volatile("s_waitcnt vmcnt(4)" ::: "memory"); }
        __builtin_amdgcn_s_barrier();
        __builtin_amdgcn_sched_barrier(0);

        FIXUP(t, t & 1)
        if (t < NT - 1) STAGE_DMA(t + 1, (t + 1) & 1)  // flies under compute
        COMPUTE(t & 1, t)
    }

#undef STAGE_DMA
#undef FIXUP
#undef LOADROW
#undef COMPUTE
}

extern "C" void kernel_launch(void* const* d_in, const int* in_sizes, int n_in,
                              void* d_out, int out_size, void* d_ws, size_t ws_size,
                              hipStream_t stream) {
    const float* mask = (const float*)d_in[0];
    const float* bs   = (const float*)d_in[1];
    const float* es   = (const float*)d_in[2];
    const float* ft   = (const float*)d_in[3];
    float* out = (float*)d_out;

    dim3 grid(GX, GY, NB);   // 8 x 4 x 16 = 512 blocks
    aes_kernel<<<grid, 256, 0, stream>>>(mask, bs, es, ft, out);
}

// Round 14
// 34.711 us; speedup vs baseline: 2.3098x; 1.3048x over previous
//
#include <hip/hip_runtime.h>

#define NB 16
#define HH 1024
#define WW 1024
#define TW 128         // tile width  (output)
#define TH 32          // tile height (output)
#define LC 136         // staged cols: global x in [tile_x-4, tile_x+132)
#define LR 36          // staged rows: global y in [tile_y-2, tile_y+34)
#define N4 (LR * (LC / 4))   // float4 tiles to stage = 1224
#define NSTG 5               // ceil(N4 / 256)

#define EPS1 2e-4f     // edge-threshold confidence margin (f32 err bound ~3e-6)
#define EPS2 1e-4f     // final-threshold confidence margin (f32 err bound ~2e-5)

typedef float f32x4 __attribute__((ext_vector_type(4)));
typedef float f32x2 __attribute__((ext_vector_type(2)));

// Cold exact-path: recompute one pixel in f64 from LDS (identical math to the
// R1 kernel that scored absmax 0.0 against the np/f64 reference).
__device__ __noinline__ float aes_exact(const float (*raw)[LC], int lr, int lc,
                                        float bsf, float esf, float fthr)
{
    const double bfd   = (double)bsf / 3.0;
    const double ethrd = 0.5 * (double)esf;
    const double fthrd = (double)fthr;
    const double w25d  = (double)(1.0f / 25.0f);

    double s25 = 0.0, s9 = 0.0;
    for (int dy = 0; dy < 5; ++dy)
        for (int dx = 0; dx < 5; ++dx) {
            double v = (double)raw[lr + dy][lc + dx];
            s25 += v;
            if (dy >= 1 && dy <= 3 && dx >= 1 && dx <= 3) s9 += v;
        }
    double c      = (double)raw[lr + 2][lc + 2];
    double edges  = fabs(9.0 * c - s9);
    double sbase  = s25 * w25d;
    double smooth = c * (1.0 - bfd) + sbase * bfd;
    double result = (edges > ethrd) ? smooth : c;
    return (result > fthrd) ? 1.0f : 0.0f;
}

__global__ __launch_bounds__(256, 4)
void aes_kernel(const float* __restrict__ mask,
                const float* __restrict__ blur_strength,
                const float* __restrict__ edge_sensitivity,
                const float* __restrict__ final_threshold,
                float* __restrict__ out)
{
    __shared__ float raw[2][LR][LC];   // 39,168 B -> 4 blocks/CU

    const int b      = blockIdx.z;
    const int tile_y = blockIdx.y * TH;
    const int tx0    = blockIdx.x * (2 * TW);   // this block: tiles tx0, tx0+TW
    const float* m = mask + (size_t)b * (HH * WW);

    const float bsf    = blur_strength[b];
    const float esf    = edge_sensitivity[b];
    const float fthr   = final_threshold[b];
    const float ethr   = 0.5f * esf;          // exact in f32
    const float bff    = bsf / 3.0f;
    const float onembf = 1.0f - bff;
    const float w25f   = 1.0f / 25.0f;

    // thread -> 4 cols x 4 rows micro-tile
    const int tx  = threadIdx.x & 31;
    const int ty  = threadIdx.x >> 5;
    const int lr0 = ty * 4;
    const int lc0 = 4 * tx + 2;

    f32x4 stg[NSTG];   // in-flight staging registers (static index via unroll)

#define STAGE_LOAD(TILE_X)                                                  \
    {                                                                       \
        _Pragma("unroll")                                                   \
        for (int k = 0; k < NSTG; ++k) {                                    \
            int i = (int)threadIdx.x + k * 256;                             \
            f32x4 v = {0.f, 0.f, 0.f, 0.f};                                 \
            if (i < N4) {                                                   \
                int row = i / (LC / 4);                                     \
                int c4  = i - row * (LC / 4);                               \
                int gy  = tile_y - 2 + row;                                 \
                int gx  = (TILE_X) - 4 + 4 * c4;    /* 16B aligned */       \
                if ((unsigned)gy < (unsigned)HH && (unsigned)gx < (unsigned)WW) \
                    v = *(const f32x4*)(m + (size_t)gy * WW + gx);          \
            }                                                               \
            stg[k] = v;                                                     \
        }                                                                   \
    }

#define STAGE_WRITE(BUF)                                                    \
    {                                                                       \
        _Pragma("unroll")                                                   \
        for (int k = 0; k < NSTG; ++k) {                                    \
            int i = (int)threadIdx.x + k * 256;                             \
            if (i < N4) {                                                   \
                int row = i / (LC / 4);                                     \
                int c4  = i - row * (LC / 4);                               \
                *(f32x4*)&raw[(BUF)][row][4 * c4] = stg[k];                 \
            }                                                               \
        }                                                                   \
    }

    // vectorized row load: h3 = (B+D)+C, h5 = (A+E)+h3  (4 vec-adds total)
#define LOADROWV(RB, ROWIDX, K)                                             \
    {                                                                       \
        const float* rp = &RB[(ROWIDX)][0];                                 \
        f32x2 u0 = *(const f32x2*)(rp + lc0);          /* a0 a1 */          \
        f32x4 u1 = *(const f32x4*)(rp + lc0 + 2);      /* a2..a5 */         \
        f32x2 u2 = *(const f32x2*)(rp + lc0 + 6);      /* a6 a7 */          \
        f32x4 A = {u0.x, u0.y, u1.x, u1.y};                                 \
        f32x4 B = {u0.y, u1.x, u1.y, u1.z};                                 \
        f32x4 D = {u1.y, u1.z, u1.w, u2.x};                                 \
        f32x4 E = {u1.z, u1.w, u2.x, u2.y};                                 \
        f32x4 h3v = (B + D) + u1;                                           \
        h3r[(K)] = h3v;                                                     \
        h5r[(K)] = (A + E) + h3v;                                           \
        ccr[(K)] = u1;                                                      \
    }

    // ---- compute one 128x32 tile from LDS buffer BUF (vectorized math) ----
#define COMPUTE(BUF, TILE_X)                                                \
    {                                                                       \
        const float (*rb)[LC] = raw[(BUF)];                                 \
        f32x4 h5r[5], h3r[5], ccr[5];                                       \
        _Pragma("unroll")                                                   \
        for (int k = 0; k < 4; ++k)                                         \
            LOADROWV(rb, lr0 + k, k)                                        \
        f32x4 S25 = (h5r[0] + h5r[1]) + (h5r[2] + h5r[3]);  /* 4 rows */    \
        float* op = out + (size_t)b * (HH * WW)                             \
                        + (size_t)(tile_y + ty * 4) * WW + (TILE_X) + 4 * tx; \
        _Pragma("unroll")                                                   \
        for (int r = 0; r < 4; ++r) {                                       \
            LOADROWV(rb, lr0 + r + 4, (r + 4) % 5)                          \
            const int i1 = (r + 1) % 5, i2 = (r + 2) % 5, i3 = (r + 3) % 5; \
            const int i4 = (r + 4) % 5;                                     \
            f32x4 S25f = S25 + h5r[i4];                                     \
            f32x4 S9   = (h3r[i1] + h3r[i3]) + h3r[i2];                     \
            f32x4 cc   = ccr[i2];                                           \
            f32x4 e    = cc * 9.0f - S9;            /* pk_fma */            \
            f32x4 sb   = S25f * w25f;                                       \
            f32x4 sm   = cc * onembf + sb * bff;    /* pk_mul+pk_fma */     \
            f32x4 d2   = sm - fthr;                                         \
            f32x4 ov;                                                       \
            _Pragma("unroll")                                               \
            for (int c = 0; c < 4; ++c) {                                   \
                float ec  = fabsf(e[c]);            /* edges */             \
                float dd1 = ec - ethr;                                      \
                bool isedge = dd1 > 0.0f;                                   \
                bool conf = (fabsf(dd1) > EPS1) &&                          \
                            (!isedge || (fabsf(d2[c]) > EPS2));             \
                bool hit = isedge ? (d2[c] > 0.0f) : (cc[c] > fthr);        \
                float o  = hit ? 1.0f : 0.0f;                               \
                if (!conf)                                                  \
                    o = aes_exact(rb, lr0 + r, lc0 + c, bsf, esf, fthr);    \
                ov[c] = o;                                                  \
            }                                                               \
            __builtin_nontemporal_store(ov, (f32x4*)(op + (size_t)r * WW)); \
            if (r < 3) S25 = S25f - h5r[r % 5];     /* row leaves window */ \
        }                                                                   \
    }

    // ---------------- pipeline: 2 tiles, double-buffered LDS --------------
    STAGE_LOAD(tx0)          // tile 0 -> regs
    STAGE_WRITE(0)           // regs -> LDS[0]   (vmcnt wait auto-inserted)
    __syncthreads();

    STAGE_LOAD(tx0 + TW)     // tile 1 loads fly under tile 0 compute
    COMPUTE(0, tx0)
    STAGE_WRITE(1)           // wait tile-1 loads, write LDS[1]
    __syncthreads();

    COMPUTE(1, tx0 + TW)

#undef STAGE_LOAD
#undef STAGE_WRITE
#undef LOADROWV
#undef COMPUTE
}

extern "C" void kernel_launch(void* const* d_in, const int* in_sizes, int n_in,
                              void* d_out, int out_size, void* d_ws, size_t ws_size,
                              hipStream_t stream) {
    const float* mask = (const float*)d_in[0];
    const float* bs   = (const float*)d_in[1];
    const float* es   = (const float*)d_in[2];
    const float* ft   = (const float*)d_in[3];
    float* out = (float*)d_out;

    dim3 grid(WW / (2 * TW), HH / TH, NB);   // 4 x 32 x 16 = 2048 blocks
    aes_kernel<<<grid, 256, 0, stream>>>(mask, bs, es, ft, out);
}